// Round 4
// baseline (448.641 us; speedup 1.0000x reference)
//
#include <hip/hip_runtime.h>

typedef short v8s __attribute__((ext_vector_type(8)));
typedef float v4f __attribute__((ext_vector_type(4)));
typedef unsigned short u16;

#define MFMA_B16(a, b, c) __builtin_amdgcn_mfma_f32_16x16x32_bf16((a), (b), (c), 0, 0, 0)
#define XS 72     // row stride in u16 (144 B, 16B-aligned)
#define GROW 64   // guard (zero) row index for conv B-operand buffers

// fp32 -> bf16 round-to-nearest-even
__device__ __forceinline__ u16 bfr(float x) {
    unsigned u = __float_as_uint(x);
    u += 0x7fffu + ((u >> 16) & 1u);
    return (u16)(u >> 16);
}

// ---------------------------------------------------------------------------
// Fused 9-tap conv matmul: D_a[o][p] = sum_tap sum_k A_a[o][tap*64+k] *
// Xp[k][p + shift(tap)], zero-padded per 8x8 tile via guard row GROW.
// A_a: global bf16 [64][576]. Xp: LDS [p][c] (65 rows, row 64 zeroed).
// Up to NA output matrices share every B fragment. B frags cached by
// s = 2*nt + dy (9 regs serve 12 (nt,dy) pairs per (dx,half)).
// ---------------------------------------------------------------------------
template <int NA>
__device__ __forceinline__ void conv_mm(const u16* __restrict__ A0,
                                        const u16* __restrict__ A1,
                                        const u16* __restrict__ A2,
                                        const u16* __restrict__ Xp,
                                        int wv, int L, int q,
                                        v4f* __restrict__ C0,
                                        v4f* __restrict__ C1,
                                        v4f* __restrict__ C2)
{
    const int pc  = L & 7;
    const int prb = L >> 3;
#pragma unroll
    for (int nt = 0; nt < 4; ++nt) {
        C0[nt] = (v4f){0.f, 0.f, 0.f, 0.f};
        if (NA > 1) C1[nt] = (v4f){0.f, 0.f, 0.f, 0.f};
        if (NA > 2) C2[nt] = (v4f){0.f, 0.f, 0.f, 0.f};
    }
    const int arow = (16 * wv + L) * 576 + q * 8;
#pragma unroll
    for (int dx = -1; dx <= 1; ++dx) {
        const bool vc = (unsigned)(pc + dx) < 8u;
        const int cand0 = L + dx - 8;          // idx at s=0: (prb-1)*8 + pc + dx
#pragma unroll
        for (int half = 0; half < 2; ++half) {
            v8s F[9];
#pragma unroll
            for (int s = 0; s <= 8; ++s) {
                const int row = prb + s - 1;
                const bool ok = vc && ((unsigned)row < 8u);
                const int idx = ok ? (cand0 + 8 * s) : GROW;
                F[s] = *(const v8s*)(Xp + idx * XS + half * 32 + q * 8);
            }
#pragma unroll
            for (int dy = -1; dy <= 1; ++dy) {
                const int tap = (dy + 1) * 3 + (dx + 1);
                const int ao = arow + tap * 64 + half * 32;
                v8s a0 = *(const v8s*)(A0 + ao);
                v8s a1 = a0, a2 = a0;
                if (NA > 1) a1 = *(const v8s*)(A1 + ao);
                if (NA > 2) a2 = *(const v8s*)(A2 + ao);
#pragma unroll
                for (int nt = 0; nt < 4; ++nt) {
                    v8s b = F[nt * 2 + dy + 1];
                    C0[nt] = MFMA_B16(a0, b, C0[nt]);
                    if (NA > 1) C1[nt] = MFMA_B16(a1, b, C1[nt]);
                    if (NA > 2) C2[nt] = MFMA_B16(a2, b, C2[nt]);
                }
            }
        }
    }
}

// 64x64x64: D[m][n] = sum_k A[m][k]*B[n][k], both bf16 LDS, wave-stripe rows.
__device__ __forceinline__ void mm_lds(const u16* __restrict__ Am,
                                       const u16* __restrict__ Bm,
                                       int wv, int L, int q, v4f C[4])
{
#pragma unroll
    for (int nt = 0; nt < 4; ++nt) C[nt] = (v4f){0.f, 0.f, 0.f, 0.f};
#pragma unroll
    for (int kt = 0; kt < 2; ++kt) {
        v8s a = *(const v8s*)(Am + (16 * wv + L) * XS + kt * 32 + q * 8);
#pragma unroll
        for (int nt = 0; nt < 4; ++nt) {
            v8s b = *(const v8s*)(Bm + (nt * 16 + L) * XS + kt * 32 + q * 8);
            C[nt] = MFMA_B16(a, b, C[nt]);
        }
    }
}

// L2-normalize rows of C-frag (rows rowb+r, cols L+16nt), write bf16 [c][p].
__device__ __forceinline__ void norm_write(const v4f C[4], u16* __restrict__ M,
                                           int rowb, int L)
{
#pragma unroll
    for (int r = 0; r < 4; ++r) {
        float ss = C[0][r] * C[0][r] + C[1][r] * C[1][r]
                 + C[2][r] * C[2][r] + C[3][r] * C[3][r];
        ss += __shfl_xor(ss, 1);
        ss += __shfl_xor(ss, 2);
        ss += __shfl_xor(ss, 4);
        ss += __shfl_xor(ss, 8);
        const float sc = 1.0f / fmaxf(sqrtf(ss), 1e-12f);
#pragma unroll
        for (int nt = 0; nt < 4; ++nt)
            M[(rowb + r) * XS + L + 16 * nt] = bfr(C[nt][r] * sc);
    }
}

// Write C-frag transposed: M[p][c] from D[c][p] (c=rowb+r, p=L+16nt).
__device__ __forceinline__ void tr_write(const v4f C[4], u16* __restrict__ M,
                                         int rowb, int L)
{
#pragma unroll
    for (int nt = 0; nt < 4; ++nt)
#pragma unroll
        for (int r = 0; r < 4; ++r)
            M[(L + 16 * nt) * XS + rowb + r] = bfr(C[nt][r]);
}

// softmax over rows in S[4] C-frags, write A bf16 to Am (wave-local rows).
__device__ __forceinline__ void softmax_to_lds(v4f S[4], float invt,
                                               u16* __restrict__ Am,
                                               int rowb, int L)
{
#pragma unroll
    for (int nt = 0; nt < 4; ++nt) S[nt] *= invt;
#pragma unroll
    for (int r = 0; r < 4; ++r) {
        float mx = fmaxf(fmaxf(S[0][r], S[1][r]), fmaxf(S[2][r], S[3][r]));
        mx = fmaxf(mx, __shfl_xor(mx, 1));
        mx = fmaxf(mx, __shfl_xor(mx, 2));
        mx = fmaxf(mx, __shfl_xor(mx, 4));
        mx = fmaxf(mx, __shfl_xor(mx, 8));
        float e0 = __expf(S[0][r] - mx);
        float e1 = __expf(S[1][r] - mx);
        float e2 = __expf(S[2][r] - mx);
        float e3 = __expf(S[3][r] - mx);
        float sm = e0 + e1 + e2 + e3;
        sm += __shfl_xor(sm, 1);
        sm += __shfl_xor(sm, 2);
        sm += __shfl_xor(sm, 4);
        sm += __shfl_xor(sm, 8);
        const float ri = 1.0f / sm;
        Am[(rowb + r) * XS + L +  0] = bfr(e0 * ri);
        Am[(rowb + r) * XS + L + 16] = bfr(e1 * ri);
        Am[(rowb + r) * XS + L + 32] = bfr(e2 * ri);
        Am[(rowb + r) * XS + L + 48] = bfr(e3 * ri);
    }
}

// ---------------------------------------------------------------------------
// Weight prep. 8 regions of 36864 bf16 each:
// 0: k1 Q fused = qk_dw[c,tap]*qk_w[c,k]        1: k1 K fused (rows 64..127)
// 2: k1 V fused = v_dw*v_w                       3: k1 proj [o][tap*64+c]
// 4,5,6: k2 Q/K/V fused from qkv1 (rows 0/64/128)  7: k2 proj1
// Products computed in fp32 from original fp32 weights, rounded once.
// ---------------------------------------------------------------------------
__global__ void prep(const float* __restrict__ qk_w, const float* __restrict__ qk_dw,
                     const float* __restrict__ v_w, const float* __restrict__ v_dw,
                     const float* __restrict__ qkv_w, const float* __restrict__ qkv_dw,
                     const float* __restrict__ pw0, const float* __restrict__ pw1,
                     u16* __restrict__ Wb)
{
    const int i = blockIdx.x * 256 + threadIdx.x;   // 0..294911
    const int reg = i / 36864, j = i % 36864;
    const int o = j / 576, kk = j % 576;
    const int tap = kk >> 6, k = kk & 63;
    float v;
    switch (reg) {
        case 0: v = qk_dw[o * 9 + tap] * qk_w[o * 64 + k]; break;
        case 1: v = qk_dw[(o + 64) * 9 + tap] * qk_w[(o + 64) * 64 + k]; break;
        case 2: v = v_dw[o * 9 + tap] * v_w[o * 64 + k]; break;
        case 3: v = pw0[o * 576 + k * 9 + tap]; break;
        case 4: v = qkv_dw[o * 9 + tap] * qkv_w[o * 64 + k]; break;
        case 5: v = qkv_dw[(o + 64) * 9 + tap] * qkv_w[(o + 64) * 64 + k]; break;
        case 6: v = qkv_dw[(o + 128) * 9 + tap] * qkv_w[(o + 128) * 64 + k]; break;
        default: v = pw1[o * 576 + k * 9 + tap]; break;
    }
    Wb[i] = bfr(v);
}

// ---------------------------------------------------------------------------
// Branch 1. LDS: 4 x 65*72*2 B = 37.4 KB -> 4 blocks/CU.
// ---------------------------------------------------------------------------
__global__ __launch_bounds__(256, 4) void k1(
    const float* __restrict__ x, const float* __restrict__ xf,
    const float* __restrict__ temp_p,
    const u16* __restrict__ Wq, const u16* __restrict__ Wk,
    const u16* __restrict__ Wv, const u16* __restrict__ Wp,
    u16* __restrict__ midb)
{
    __shared__ u16 B0[65 * XS], B1[65 * XS], B2[65 * XS], B3[65 * XS];
    const int t = threadIdx.x, n = blockIdx.x;
    const int lane = t & 63, wv = t >> 6, L = lane & 15, q = lane >> 4;
    const int rowb = 16 * wv + 4 * q;
    const size_t base = (size_t)n << 12;
    const float invt = 1.0f / temp_p[0];
    const int yp = t >> 4, xx0 = (t & 15) << 4;
    const int c2b = (yp >> 3) << 5, ir = (yp & 7) << 3;

    if (t < 64) {   // zero guard rows
        B0[GROW * XS + t] = 0; B1[GROW * XS + t] = 0;
        B2[GROW * XS + t] = 0; B3[GROW * XS + t] = 0;
    }
    {   // Xf -> B0, X -> B3, both bf16 [p][c]
        const float* sf = xf + base + yp * 256 + xx0;
        const float* sx = x  + base + yp * 256 + xx0;
#pragma unroll
        for (int k = 0; k < 4; ++k) {
            float4 a = *(const float4*)(sf + 4 * k);
            float4 b = *(const float4*)(sx + 4 * k);
            const int xx = xx0 + 4 * k;
            const int c = c2b + (xx >> 3), pb = ir + (xx & 7);
            B0[(pb + 0) * XS + c] = bfr(a.x); B0[(pb + 1) * XS + c] = bfr(a.y);
            B0[(pb + 2) * XS + c] = bfr(a.z); B0[(pb + 3) * XS + c] = bfr(a.w);
            B3[(pb + 0) * XS + c] = bfr(b.x); B3[(pb + 1) * XS + c] = bfr(b.y);
            B3[(pb + 2) * XS + c] = bfr(b.z); B3[(pb + 3) * XS + c] = bfr(b.w);
        }
    }
    __syncthreads();                                  // 1
    v4f CQ[4], CK[4], CV[4], Cd[4];
    conv_mm<2>(Wq, Wk, nullptr, B0, wv, L, q, CQ, CK, Cd);   // fused 1x1+dw Q,K
    conv_mm<1>(Wv, nullptr, nullptr, B3, wv, L, q, CV, Cd, Cd); // fused V
    norm_write(CQ, B1, rowb, L);                      // Qhat -> B1 [c][p]
    norm_write(CK, B2, rowb, L);                      // Khat -> B2 [c][p]
    __syncthreads();                                  // 2
    v4f S[4];
    mm_lds(B1, B2, wv, L, q, S);                      // S = Qhat @ Khat^T
    softmax_to_lds(S, invt, B0, rowb, L);             // A -> B0 (Xf dead)
    tr_write(CV, B3, rowb, L);                        // V^T -> B3 (X dead)
    __syncthreads();                                  // 3
    v4f O[4];
    mm_lds(B0, B3, wv, L, q, O);                      // O = A @ V
    tr_write(O, B1, rowb, L);                         // O^T -> B1 [p][c]
    __syncthreads();                                  // 4
    v4f CP[4];
    conv_mm<1>(Wp, nullptr, nullptr, B1, wv, L, q, CP, Cd, Cd); // proj 3x3
#pragma unroll
    for (int nt = 0; nt < 4; ++nt)
#pragma unroll
        for (int r = 0; r < 4; ++r) {
            const int o = rowb + r, p = L + 16 * nt;
            const int yy = ((o >> 5) << 3) + (p >> 3);
            const int xp = ((o & 31) << 3) + (p & 7);
            midb[base + yy * 256 + xp] = bfr(CP[nt][r]);
        }
}

// ---------------------------------------------------------------------------
// Branch 2: reads mid (bf16) with roll(-4,-4); writes fp32 out with roll(+4,+4).
// ---------------------------------------------------------------------------
__global__ __launch_bounds__(256, 4) void k2(
    const u16* __restrict__ midb, const float* __restrict__ temp_p,
    const u16* __restrict__ Wq, const u16* __restrict__ Wk,
    const u16* __restrict__ Wv, const u16* __restrict__ Wp,
    float* __restrict__ out)
{
    __shared__ u16 B0[65 * XS], B1[65 * XS], B2[65 * XS], B3[65 * XS];
    const int t = threadIdx.x, m = blockIdx.x;
    const int lane = t & 63, wv = t >> 6, L = lane & 15, q = lane >> 4;
    const int rowb = 16 * wv + 4 * q;
    const int plane = m >> 4, mh2 = m & 15;
    const u16* img = midb + ((size_t)plane << 16);
    const float invt = 1.0f / temp_p[0];

    if (t < 64) {
        B0[GROW * XS + t] = 0; B1[GROW * XS + t] = 0;
        B2[GROW * XS + t] = 0; B3[GROW * XS + t] = 0;
    }
    {   // shifted strip -> B0 [p][c] (pure bf16 copy)
        const int yp = t >> 4, xx0 = (t & 15) << 4;
        const int c2b = (yp >> 3) << 5, ir = (yp & 7) << 3;
        const int row = (mh2 * 16 + 4 + yp) & 255;
#pragma unroll
        for (int k = 0; k < 4; ++k) {
            const int cc = (xx0 + 4 + 4 * k) & 255;
            ushort4 a = *(const ushort4*)(img + row * 256 + cc);
            const int xx = xx0 + 4 * k;
            const int c = c2b + (xx >> 3), pb = ir + (xx & 7);
            B0[(pb + 0) * XS + c] = a.x;
            B0[(pb + 1) * XS + c] = a.y;
            B0[(pb + 2) * XS + c] = a.z;
            B0[(pb + 3) * XS + c] = a.w;
        }
    }
    __syncthreads();                                  // 1
    v4f CQ[4], CK[4], CV[4], Cd[4];
    conv_mm<3>(Wq, Wk, Wv, B0, wv, L, q, CQ, CK, CV); // fused QKV (shared B)
    norm_write(CQ, B1, rowb, L);
    norm_write(CK, B2, rowb, L);
    tr_write(CV, B3, rowb, L);                        // V^T -> B3
    __syncthreads();                                  // 2
    v4f S[4];
    mm_lds(B1, B2, wv, L, q, S);
    softmax_to_lds(S, invt, B0, rowb, L);             // A -> B0 (strip dead)
    __syncthreads();                                  // 3
    v4f O[4];
    mm_lds(B0, B3, wv, L, q, O);
    tr_write(O, B1, rowb, L);                         // O^T -> B1
    __syncthreads();                                  // 4
    v4f CP[4];
    conv_mm<1>(Wp, nullptr, nullptr, B1, wv, L, q, CP, Cd, Cd);
    float* op = out + ((size_t)plane << 16);
#pragma unroll
    for (int nt = 0; nt < 4; ++nt)
#pragma unroll
        for (int r = 0; r < 4; ++r) {
            const int o = rowb + r, p = L + 16 * nt;
            const int R = mh2 * 16 + ((o >> 5) << 3) + (p >> 3);
            const int orow = (R + 4) & 255;
            const int ocol = ((o & 31) * 8 + (p & 7) + 4) & 255;
            op[orow * 256 + ocol] = CP[nt][r];
        }
}

extern "C" void kernel_launch(void* const* d_in, const int* in_sizes, int n_in,
                              void* d_out, int out_size, void* d_ws, size_t ws_size,
                              hipStream_t stream)
{
    const float* x       = (const float*)d_in[0];
    const float* xf      = (const float*)d_in[1];
    const float* temp    = (const float*)d_in[2];
    const float* qk_w    = (const float*)d_in[3];
    const float* qk_dw   = (const float*)d_in[4];
    const float* v_w     = (const float*)d_in[5];
    const float* v_dw    = (const float*)d_in[6];
    const float* proj_w  = (const float*)d_in[7];
    const float* proj1_w = (const float*)d_in[8];
    const float* qkv1_w  = (const float*)d_in[9];
    const float* qkv1_dw = (const float*)d_in[10];
    float* out = (float*)d_out;

    u16* midb = (u16*)d_ws;                               // 33554432 B
    u16* Wb   = (u16*)((char*)d_ws + 33554432);           // 589824 B

    prep<<<1152, 256, 0, stream>>>(qk_w, qk_dw, v_w, v_dw, qkv1_w, qkv1_dw,
                                   proj_w, proj1_w, Wb);
    k1<<<4096, 256, 0, stream>>>(x, xf, temp,
                                 Wb, Wb + 36864, Wb + 73728, Wb + 110592, midb);
    k2<<<4096, 256, 0, stream>>>(midb, temp,
                                 Wb + 147456, Wb + 184320, Wb + 221184, Wb + 258048,
                                 out);
}